// Round 6
// baseline (350.097 us; speedup 1.0000x reference)
//
#include <hip/hip_runtime.h>
#include <cstdint>

typedef uint16_t u16;
typedef __attribute__((ext_vector_type(8))) short bf16x8;
typedef __attribute__((ext_vector_type(4))) short bf16x4;
typedef __attribute__((ext_vector_type(4))) float f32x4;

// 0.125 * log2(e): folded into Q projection so softmax is exp2(s) directly.
#define QSCALE 0.18033688011112042f

struct Ptr3 { const float* a; const float* b; const float* c; };

__device__ __forceinline__ u16 f2bf(float x) {
  union { float f; uint32_t u; } v; v.f = x;
  uint32_t r = (v.u + 0x7fffu + ((v.u >> 16) & 1u)) >> 16;
  return (u16)r;
}

// async global->LDS, 16B per lane. LDS dest is wave-uniform base + lane*16.
__device__ __forceinline__ void async16(void* lds, const void* g) {
  __builtin_amdgcn_global_load_lds((const __attribute__((address_space(1))) void*)g,
                                   (__attribute__((address_space(3))) void*)lds, 16, 0, 0);
}

// ---------------- fused elementwise f32 -> bf16 (3 tensors) ----------------
__global__ __launch_bounds__(256) void k_cast3(Ptr3 in, u16* __restrict__ out) {
  const int z = blockIdx.y;
  const float* p = z == 0 ? in.a : (z == 1 ? in.b : in.c);
  int i = blockIdx.x * 256 + threadIdx.x;
  float4 v = ((const float4*)p)[i];
  bf16x4 o;
  o[0] = (short)f2bf(v.x); o[1] = (short)f2bf(v.y);
  o[2] = (short)f2bf(v.z); o[3] = (short)f2bf(v.w);
  *(bf16x4*)(out + (long)z * 4194304 + (long)i * 4) = o;
}

// ---------------- fused Wq/Wk/Wv transpose: grid (16,1,48) ----------------
// W[h][d][k] (f32, 1024x64 per head) -> wt[w][h*64+k][d] (bf16). stride 65 = odd.
__global__ __launch_bounds__(256) void k_transpose_w(Ptr3 w, u16* __restrict__ out) {
  __shared__ u16 tile[64 * 65];
  const int t = threadIdx.x;
  const int z = blockIdx.z;
  const float* in = (z < 16) ? w.a : (z < 32 ? w.b : w.c);
  const long in_base = (long)(z & 15) * 65536;
  const long out_base = (long)z * 65536;
  const int r0 = blockIdx.x * 64;
  for (int e = t; e < 4096; e += 256) {
    int rr = e >> 6, cc = e & 63;
    tile[rr * 65 + cc] = f2bf(in[in_base + (long)(r0 + rr) * 64 + cc]);
  }
  __syncthreads();
  for (int s = t; s < 512; s += 256) {
    int cc = s >> 3, r8 = (s & 7) << 3;
    bf16x8 p;
    #pragma unroll
    for (int j = 0; j < 8; ++j) p[j] = (short)tile[(r8 + j) * 65 + cc];
    *(bf16x8*)(out + out_base + (long)cc * 1024 + r0 + r8) = p;
  }
}

// ---------------- generic tiled transpose -> bf16 (out_w only now) --------
__global__ __launch_bounds__(256) void k_transpose_bf16(const void* __restrict__ in,
                                                        int in_is_f32, u16* __restrict__ out,
                                                        int rstride, int R, int sph,
                                                        long slab_lo, long slab_hi) {
  __shared__ u16 tile[64 * 65];
  const int t = threadIdx.x;
  const long z = blockIdx.z;
  const long in_base = (z / sph) * slab_hi + (z % sph) * slab_lo;
  const long out_base = z * (long)R * (long)(gridDim.y * 64);
  const int r0 = blockIdx.x * 64, c0 = blockIdx.y * 64;
  for (int e = t; e < 4096; e += 256) {
    int rr = e >> 6, cc = e & 63;
    long src = in_base + (long)(r0 + rr) * rstride + c0 + cc;
    u16 w = in_is_f32 ? f2bf(((const float*)in)[src]) : ((const u16*)in)[src];
    tile[rr * 65 + cc] = w;
  }
  __syncthreads();
  for (int s = t; s < 512; s += 256) {
    int cc = s >> 3, r8 = (s & 7) << 3;
    bf16x8 p;
    #pragma unroll
    for (int j = 0; j < 8; ++j) p[j] = (short)tile[(r8 + j) * 65 + cc];
    *(bf16x8*)(out + out_base + (long)(c0 + cc) * R + r0 + r8) = p;
  }
}

// ---------------- fused QKV GEMM: 128x128 tile, grid (8,32,3) --------------
// R4-proven async16 m97 structure. C bf16 = (A*Bt^T)*scale.
__global__ __launch_bounds__(256) void k_gemm_qkv(const u16* __restrict__ A0,
                                                  const u16* __restrict__ B0,
                                                  u16* __restrict__ C0, float scale0) {
  __shared__ __align__(16) u16 As[128 * 32];
  __shared__ __align__(16) u16 Bs[128 * 32];
  const int z = blockIdx.z;
  const u16* A = A0 + (long)z * 4194304;
  const u16* Bt = B0 + (long)z * 1048576;
  u16* C = C0 + (long)z * 4194304;
  const float scale = z ? 1.0f : scale0;
  const int t = threadIdx.x, lane = t & 63, quad = lane >> 4, l16 = lane & 15;
  const int wave = t >> 6, wy = wave >> 1, wx = wave & 1;
  const int m0 = blockIdx.y * 128, n0 = blockIdx.x * 128;
  const int wbase = t & 192;
  f32x4 acc[4][4] = {};
  for (int k0 = 0; k0 < 1024; k0 += 32) {
    __syncthreads();
    #pragma unroll
    for (int i = 0; i < 2; ++i) {
      int sb = i * 256 + wbase;
      int s = sb + lane;
      int row = s >> 2, c = s & 3;
      async16(As + sb * 8, A + (long)(m0 + row) * 1024 + k0 + c * 8);
      async16(Bs + sb * 8, Bt + (long)(n0 + row) * 1024 + k0 + c * 8);
    }
    __syncthreads();
    bf16x8 af[4], bfr[4];
    #pragma unroll
    for (int mt = 0; mt < 4; ++mt)
      af[mt] = *(const bf16x8*)(As + (wy * 64 + mt * 16 + l16) * 32 + quad * 8);
    #pragma unroll
    for (int nt = 0; nt < 4; ++nt)
      bfr[nt] = *(const bf16x8*)(Bs + (wx * 64 + nt * 16 + l16) * 32 + quad * 8);
    #pragma unroll
    for (int mt = 0; mt < 4; ++mt)
      #pragma unroll
      for (int nt = 0; nt < 4; ++nt)
        acc[mt][nt] = __builtin_amdgcn_mfma_f32_16x16x32_bf16(af[mt], bfr[nt], acc[mt][nt], 0, 0, 0);
  }
  #pragma unroll
  for (int mt = 0; mt < 4; ++mt)
    #pragma unroll
    for (int nt = 0; nt < 4; ++nt) {
      int col = n0 + wx * 64 + nt * 16 + l16;
      #pragma unroll
      for (int r = 0; r < 4; ++r) {
        int row = m0 + wy * 64 + mt * 16 + quad * 4 + r;
        C[(long)row * 1024 + col] = f2bf(acc[mt][nt][r] * scale);
      }
    }
}

// ---- out-proj GEMM: 128x64 tile, grid (16,32), async16, f32 out + bias ----
__global__ __launch_bounds__(256) void k_gemm_out(const u16* __restrict__ A,
                                                  const u16* __restrict__ Bt,
                                                  float* __restrict__ C,
                                                  const float* __restrict__ bias) {
  __shared__ __align__(16) u16 As[128 * 32];
  __shared__ __align__(16) u16 Bs[64 * 32];
  const int t = threadIdx.x, lane = t & 63, quad = lane >> 4, l16 = lane & 15;
  const int wave = t >> 6;
  const int m0 = blockIdx.y * 128, n0 = blockIdx.x * 64;
  const int wbase = t & 192;
  f32x4 acc[2][4] = {};
  for (int k0 = 0; k0 < 1024; k0 += 32) {
    __syncthreads();
    #pragma unroll
    for (int i = 0; i < 2; ++i) {
      int sb = i * 256 + wbase;
      int s = sb + lane;
      int row = s >> 2, c = s & 3;
      async16(As + sb * 8, A + (long)(m0 + row) * 1024 + k0 + c * 8);
    }
    {
      int s = t;
      int row = s >> 2, c = s & 3;
      async16(Bs + wbase * 8, Bt + (long)(n0 + row) * 1024 + k0 + c * 8);
    }
    __syncthreads();
    bf16x8 af[2], bfr[4];
    #pragma unroll
    for (int mt = 0; mt < 2; ++mt)
      af[mt] = *(const bf16x8*)(As + (wave * 32 + mt * 16 + l16) * 32 + quad * 8);
    #pragma unroll
    for (int nt = 0; nt < 4; ++nt)
      bfr[nt] = *(const bf16x8*)(Bs + (nt * 16 + l16) * 32 + quad * 8);
    #pragma unroll
    for (int mt = 0; mt < 2; ++mt)
      #pragma unroll
      for (int nt = 0; nt < 4; ++nt)
        acc[mt][nt] = __builtin_amdgcn_mfma_f32_16x16x32_bf16(af[mt], bfr[nt], acc[mt][nt], 0, 0, 0);
  }
  #pragma unroll
  for (int mt = 0; mt < 2; ++mt)
    #pragma unroll
    for (int nt = 0; nt < 4; ++nt) {
      int col = n0 + nt * 16 + l16;
      #pragma unroll
      for (int r = 0; r < 4; ++r) {
        int row = m0 + wave * 32 + mt * 16 + quad * 4 + r;
        C[(long)row * 1024 + col] = acc[mt][nt][r] + bias[col];
      }
    }
}

// ---------------- flash attention v6 -------------------------------------
// 512 threads, q-tile 256 (32 rows/wave), grid 256 (bh in low 5 bits -> XCD
// L2 affinity). K/V double-buffered in LDS with register prefetch and ONE
// barrier per iteration: [barrier] -> ds_write next tile -> issue loads for
// tile+2 -> compute current. The compiler's vmcnt(0) drain at the barrier
// then covers loads issued a FULL iteration earlier.
// V is read in native (B,L,H,64) layout (same as K) and transposed into LDS
// during staging via 8 scalar ds_writes/thread -> no global V^T pass needed.
__global__ __launch_bounds__(512, 2) void k_flash(const u16* __restrict__ Qp,
                                                  const u16* __restrict__ Kp,
                                                  const u16* __restrict__ Vp,
                                                  u16* __restrict__ ctx) {
  __shared__ __align__(16) u16 qs[256 * 68];     // Q tile; per-wave P space after
  __shared__ __align__(16) u16 ks[2][64 * 68];   // K rows [l][d]
  __shared__ __align__(16) u16 vs[2][64 * 68];   // V^T [d][l]
  const int t = threadIdx.x, lane = t & 63, quad = lane >> 4, l16 = lane & 15;
  const int wave = t >> 6;                        // 0..7
  const int bh = blockIdx.x & 31, b = bh >> 4, h = bh & 15;
  const int q0 = (blockIdx.x >> 5) * 256;
  const long gkv = (long)b * 2097152 + h * 64;    // K and V share layout
  const int srow = t >> 3, sc = t & 7;            // staging: 64 rows x 8 chunks

  // ---- startup: Q (256x64, 4 slots/thread) + K/V tile 0 + prefetch tile 1
  const long gq = (long)(b * 2048 + q0) * 1024 + h * 64;
  {
    bf16x8 qr[4];
    #pragma unroll
    for (int i = 0; i < 4; ++i)
      qr[i] = *(const bf16x8*)(Qp + gq + (long)((i * 512 + t) >> 3) * 1024 + (t & 7) * 8);
    #pragma unroll
    for (int i = 0; i < 4; ++i)
      *(bf16x8*)(qs + ((i * 512 + t) >> 3) * 68 + (t & 7) * 8) = qr[i];
  }
  bf16x8 kreg = *(const bf16x8*)(Kp + gkv + (long)srow * 1024 + sc * 8);
  bf16x8 vreg = *(const bf16x8*)(Vp + gkv + (long)srow * 1024 + sc * 8);
  *(bf16x8*)(ks[0] + srow * 68 + sc * 8) = kreg;
  #pragma unroll
  for (int j = 0; j < 8; ++j) vs[0][(sc * 8 + j) * 68 + srow] = (u16)vreg[j];
  // prefetch tile 1 into regs (WAR on the ds_writes above is tracked in-order)
  kreg = *(const bf16x8*)(Kp + gkv + (long)(64 + srow) * 1024 + sc * 8);
  vreg = *(const bf16x8*)(Vp + gkv + (long)(64 + srow) * 1024 + sc * 8);
  __syncthreads();

  // Q fragments; wave w owns q-rows w*32..w*32+31 == its private P region,
  // so overwriting them after this read needs no barrier (same-wave DS order).
  bf16x8 qf[2][2];
  #pragma unroll
  for (int msub = 0; msub < 2; ++msub)
    #pragma unroll
    for (int kh = 0; kh < 2; ++kh)
      qf[msub][kh] = *(const bf16x8*)(qs + (wave * 32 + msub * 16 + l16) * 68 + kh * 32 + quad * 8);
  u16* pw = qs + wave * 32 * 68;   // per-wave P: 32 q-rows x 64 kv, stride 68

  float lsum[2][4] = {};
  f32x4 o[2][4] = {};

  for (int kt = 0; kt < 32; ++kt) {
    if (kt) __syncthreads();   // all waves done with iter kt-1

    // write tile kt+1 (loaded last iter) into the off buffer, then issue
    // loads for tile kt+2 -- they stay in flight across this whole compute.
    if (kt < 31) {
      *(bf16x8*)(ks[(kt + 1) & 1] + srow * 68 + sc * 8) = kreg;
      #pragma unroll
      for (int j = 0; j < 8; ++j)
        vs[(kt + 1) & 1][(sc * 8 + j) * 68 + srow] = (u16)vreg[j];
    }
    if (kt < 30) {
      int kv0 = (kt + 2) * 64;
      kreg = *(const bf16x8*)(Kp + gkv + (long)(kv0 + srow) * 1024 + sc * 8);
      vreg = *(const bf16x8*)(Vp + gkv + (long)(kv0 + srow) * 1024 + sc * 8);
    }

    const u16* ksb = ks[kt & 1];
    const u16* vsb = vs[kt & 1];

    // K fragments (shared by both m-subtiles)
    bf16x8 kf[4][2];
    #pragma unroll
    for (int nt = 0; nt < 4; ++nt)
      #pragma unroll
      for (int kh = 0; kh < 2; ++kh)
        kf[nt][kh] = *(const bf16x8*)(ksb + (nt * 16 + l16) * 68 + kh * 32 + quad * 8);

    // S = Q @ K^T ; p = exp2(s) ; P -> LDS row-major [q][kv]
    #pragma unroll
    for (int msub = 0; msub < 2; ++msub)
      #pragma unroll
      for (int nt = 0; nt < 4; ++nt) {
        f32x4 a = {};
        #pragma unroll
        for (int kh = 0; kh < 2; ++kh)
          a = __builtin_amdgcn_mfma_f32_16x16x32_bf16(qf[msub][kh], kf[nt][kh], a, 0, 0, 0);
        #pragma unroll
        for (int r = 0; r < 4; ++r) {
          float e = __builtin_amdgcn_exp2f(a[r]);
          lsum[msub][r] += e;
          pw[(msub * 16 + quad * 4 + r) * 68 + nt * 16 + l16] = f2bf(e);
        }
      }

    // O += P @ V   (V^T tile rows are dims -> contiguous B-fragments)
    #pragma unroll
    for (int msub = 0; msub < 2; ++msub)
      #pragma unroll
      for (int kh = 0; kh < 2; ++kh) {
        bf16x8 pa = *(const bf16x8*)(pw + (msub * 16 + l16) * 68 + kh * 32 + quad * 8);
        #pragma unroll
        for (int nt = 0; nt < 4; ++nt) {
          bf16x8 vf = *(const bf16x8*)(vsb + (nt * 16 + l16) * 68 + kh * 32 + quad * 8);
          o[msub][nt] = __builtin_amdgcn_mfma_f32_16x16x32_bf16(pa, vf, o[msub][nt], 0, 0, 0);
        }
      }
  }

  // final l reduction across the 16 kv-lanes, then normalize + write
  #pragma unroll
  for (int msub = 0; msub < 2; ++msub)
    #pragma unroll
    for (int r = 0; r < 4; ++r) {
      float l = lsum[msub][r];
      #pragma unroll
      for (int d = 1; d < 16; d <<= 1) l += __shfl_xor(l, d);
      lsum[msub][r] = 1.0f / l;
    }
  #pragma unroll
  for (int msub = 0; msub < 2; ++msub)
    #pragma unroll
    for (int nt = 0; nt < 4; ++nt)
      #pragma unroll
      for (int r = 0; r < 4; ++r) {
        int q = q0 + wave * 32 + msub * 16 + quad * 4 + r;
        long idx = (long)(b * 2048 + q) * 1024 + h * 64 + nt * 16 + l16;
        ctx[idx] = f2bf(o[msub][nt][r] * lsum[msub][r]);
      }
}

extern "C" void kernel_launch(void* const* d_in, const int* in_sizes, int n_in,
                              void* d_out, int out_size, void* d_ws, size_t ws_size,
                              hipStream_t stream) {
  const float* query = (const float*)d_in[0];
  const float* key   = (const float*)d_in[1];
  const float* value = (const float*)d_in[2];
  const float* Wq    = (const float*)d_in[3];
  const float* Wk    = (const float*)d_in[4];
  const float* Wv    = (const float*)d_in[5];
  const float* out_w = (const float*)d_in[6];
  const float* out_b = (const float*)d_in[7];
  // d_in[8] = coupling: unused — per-head scalar bias is softmax-invariant.
  float* out = (float*)d_out;

  char* ws = (char*)d_ws;
  size_t off = 0;
  auto alloc = [&](size_t bytes) {
    void* p = ws + off;
    off += (bytes + 255) & ~(size_t)255;
    return p;
  };
  // qb,kb,vb contiguous; wtq,wtk,wtv contiguous; Qp,Kp,Vp contiguous —
  // k_cast3 / k_transpose_w / k_gemm_qkv index them by z-stride.
  u16* qb  = (u16*)alloc(4096L * 1024 * 2);
  u16* kb  = (u16*)alloc(4096L * 1024 * 2);
  u16* vb  = (u16*)alloc(4096L * 1024 * 2);
  u16* wtq = (u16*)alloc(1024L * 1024 * 2);
  u16* wtk = (u16*)alloc(1024L * 1024 * 2);
  u16* wtv = (u16*)alloc(1024L * 1024 * 2);
  u16* wto = (u16*)alloc(1024L * 1024 * 2);
  u16* Qp  = (u16*)alloc(4096L * 1024 * 2);
  u16* Kp  = (u16*)alloc(4096L * 1024 * 2);
  u16* Vp  = (u16*)alloc(4096L * 1024 * 2);
  u16* ctx = qb;  // reuse: query-bf16 dead after Q projection
  (void)kb; (void)vb; (void)wtk; (void)wtv; (void)Kp; (void)Vp;

  // inputs -> bf16 (fused, grid.y selects tensor)
  k_cast3<<<dim3(4096, 3), 256, 0, stream>>>(Ptr3{query, key, value}, qb);

  // Wq/Wk/Wv -> Bt (NxK) bf16 (fused).  wt[w][h*64+k][d] = W[w][h][d][k]
  k_transpose_w<<<dim3(16, 1, 48), 256, 0, stream>>>(Ptr3{Wq, Wk, Wv}, wtq);
  // out_w (K x N) -> wto (N x K)
  k_transpose_bf16<<<dim3(16, 16, 1), 256, 0, stream>>>(out_w, 1, wto, 1024, 1024, 1, 0L, 0L);

  // fused Q,K,V projections (Q pre-scaled by 0.125*log2(e))
  k_gemm_qkv<<<dim3(8, 32, 3), 256, 0, stream>>>(qb, wtq, Qp, QSCALE);

  // attention: grid 256 = 8 q-tiles x 32 bh, bh in low 5 bits for XCD affinity.
  // V consumed in native layout (in-LDS transpose during staging).
  k_flash<<<256, 512, 0, stream>>>(Qp, Kp, Vp, ctx);

  // output projection + bias -> f32
  k_gemm_out<<<dim3(16, 32), 256, 0, stream>>>(ctx, wto, out, out_b);
}

// Round 7
// 264.741 us; speedup vs baseline: 1.3224x; 1.3224x over previous
//
#include <hip/hip_runtime.h>
#include <cstdint>

typedef uint16_t u16;
typedef __attribute__((ext_vector_type(8))) short bf16x8;
typedef __attribute__((ext_vector_type(4))) short bf16x4;
typedef __attribute__((ext_vector_type(4))) float f32x4;

// 0.125 * log2(e): folded into Q projection so softmax is exp2(s) directly.
#define QSCALE 0.18033688011112042f

struct Ptr3 { const float* a; const float* b; const float* c; };

__device__ __forceinline__ u16 f2bf(float x) {
  union { float f; uint32_t u; } v; v.f = x;
  uint32_t r = (v.u + 0x7fffu + ((v.u >> 16) & 1u)) >> 16;
  return (u16)r;
}

// async global->LDS, 16B per lane. LDS dest is wave-uniform base + lane*16.
__device__ __forceinline__ void async16(void* lds, const void* g) {
  __builtin_amdgcn_global_load_lds((const __attribute__((address_space(1))) void*)g,
                                   (__attribute__((address_space(3))) void*)lds, 16, 0, 0);
}

// ---------------- fused elementwise f32 -> bf16 (3 tensors) ----------------
__global__ __launch_bounds__(256) void k_cast3(Ptr3 in, u16* __restrict__ out) {
  const int z = blockIdx.y;
  const float* p = z == 0 ? in.a : (z == 1 ? in.b : in.c);
  int i = blockIdx.x * 256 + threadIdx.x;
  float4 v = ((const float4*)p)[i];
  bf16x4 o;
  o[0] = (short)f2bf(v.x); o[1] = (short)f2bf(v.y);
  o[2] = (short)f2bf(v.z); o[3] = (short)f2bf(v.w);
  *(bf16x4*)(out + (long)z * 4194304 + (long)i * 4) = o;
}

// ---------------- fused Wq/Wk/Wv transpose: grid (16,1,48) ----------------
// W[h][d][k] (f32, 1024x64 per head) -> wt[w][h*64+k][d] (bf16). stride 65 = odd.
__global__ __launch_bounds__(256) void k_transpose_w(Ptr3 w, u16* __restrict__ out) {
  __shared__ u16 tile[64 * 65];
  const int t = threadIdx.x;
  const int z = blockIdx.z;
  const float* in = (z < 16) ? w.a : (z < 32 ? w.b : w.c);
  const long in_base = (long)(z & 15) * 65536;
  const long out_base = (long)z * 65536;
  const int r0 = blockIdx.x * 64;
  for (int e = t; e < 4096; e += 256) {
    int rr = e >> 6, cc = e & 63;
    tile[rr * 65 + cc] = f2bf(in[in_base + (long)(r0 + rr) * 64 + cc]);
  }
  __syncthreads();
  for (int s = t; s < 512; s += 256) {
    int cc = s >> 3, r8 = (s & 7) << 3;
    bf16x8 p;
    #pragma unroll
    for (int j = 0; j < 8; ++j) p[j] = (short)tile[(r8 + j) * 65 + cc];
    *(bf16x8*)(out + out_base + (long)cc * 1024 + r0 + r8) = p;
  }
}

// ---------------- generic tiled transpose -> bf16 ----------------
__global__ __launch_bounds__(256) void k_transpose_bf16(const void* __restrict__ in,
                                                        int in_is_f32, u16* __restrict__ out,
                                                        int rstride, int R, int sph,
                                                        long slab_lo, long slab_hi) {
  __shared__ u16 tile[64 * 65];
  const int t = threadIdx.x;
  const long z = blockIdx.z;
  const long in_base = (z / sph) * slab_hi + (z % sph) * slab_lo;
  const long out_base = z * (long)R * (long)(gridDim.y * 64);
  const int r0 = blockIdx.x * 64, c0 = blockIdx.y * 64;
  for (int e = t; e < 4096; e += 256) {
    int rr = e >> 6, cc = e & 63;
    long src = in_base + (long)(r0 + rr) * rstride + c0 + cc;
    u16 w = in_is_f32 ? f2bf(((const float*)in)[src]) : ((const u16*)in)[src];
    tile[rr * 65 + cc] = w;
  }
  __syncthreads();
  for (int s = t; s < 512; s += 256) {
    int cc = s >> 3, r8 = (s & 7) << 3;
    bf16x8 p;
    #pragma unroll
    for (int j = 0; j < 8; ++j) p[j] = (short)tile[(r8 + j) * 65 + cc];
    *(bf16x8*)(out + out_base + (long)(c0 + cc) * R + r0 + r8) = p;
  }
}

// ---------------- fused QKV GEMM: 128x128 tile, grid (8,32,3) --------------
// R4-proven async16 m97 structure. C bf16 = (A*Bt^T)*scale.
__global__ __launch_bounds__(256) void k_gemm_qkv(const u16* __restrict__ A0,
                                                  const u16* __restrict__ B0,
                                                  u16* __restrict__ C0, float scale0) {
  __shared__ __align__(16) u16 As[128 * 32];
  __shared__ __align__(16) u16 Bs[128 * 32];
  const int z = blockIdx.z;
  const u16* A = A0 + (long)z * 4194304;
  const u16* Bt = B0 + (long)z * 1048576;
  u16* C = C0 + (long)z * 4194304;
  const float scale = z ? 1.0f : scale0;
  const int t = threadIdx.x, lane = t & 63, quad = lane >> 4, l16 = lane & 15;
  const int wave = t >> 6, wy = wave >> 1, wx = wave & 1;
  const int m0 = blockIdx.y * 128, n0 = blockIdx.x * 128;
  const int wbase = t & 192;
  f32x4 acc[4][4] = {};
  for (int k0 = 0; k0 < 1024; k0 += 32) {
    __syncthreads();
    #pragma unroll
    for (int i = 0; i < 2; ++i) {
      int sb = i * 256 + wbase;
      int s = sb + lane;
      int row = s >> 2, c = s & 3;
      async16(As + sb * 8, A + (long)(m0 + row) * 1024 + k0 + c * 8);
      async16(Bs + sb * 8, Bt + (long)(n0 + row) * 1024 + k0 + c * 8);
    }
    __syncthreads();
    bf16x8 af[4], bfr[4];
    #pragma unroll
    for (int mt = 0; mt < 4; ++mt)
      af[mt] = *(const bf16x8*)(As + (wy * 64 + mt * 16 + l16) * 32 + quad * 8);
    #pragma unroll
    for (int nt = 0; nt < 4; ++nt)
      bfr[nt] = *(const bf16x8*)(Bs + (wx * 64 + nt * 16 + l16) * 32 + quad * 8);
    #pragma unroll
    for (int mt = 0; mt < 4; ++mt)
      #pragma unroll
      for (int nt = 0; nt < 4; ++nt)
        acc[mt][nt] = __builtin_amdgcn_mfma_f32_16x16x32_bf16(af[mt], bfr[nt], acc[mt][nt], 0, 0, 0);
  }
  #pragma unroll
  for (int mt = 0; mt < 4; ++mt)
    #pragma unroll
    for (int nt = 0; nt < 4; ++nt) {
      int col = n0 + wx * 64 + nt * 16 + l16;
      #pragma unroll
      for (int r = 0; r < 4; ++r) {
        int row = m0 + wy * 64 + mt * 16 + quad * 4 + r;
        C[(long)row * 1024 + col] = f2bf(acc[mt][nt][r] * scale);
      }
    }
}

// ---- out-proj GEMM: 128x64 tile, grid (16,32), async16, f32 out + bias ----
__global__ __launch_bounds__(256) void k_gemm_out(const u16* __restrict__ A,
                                                  const u16* __restrict__ Bt,
                                                  float* __restrict__ C,
                                                  const float* __restrict__ bias) {
  __shared__ __align__(16) u16 As[128 * 32];
  __shared__ __align__(16) u16 Bs[64 * 32];
  const int t = threadIdx.x, lane = t & 63, quad = lane >> 4, l16 = lane & 15;
  const int wave = t >> 6;
  const int m0 = blockIdx.y * 128, n0 = blockIdx.x * 64;
  const int wbase = t & 192;
  f32x4 acc[2][4] = {};
  for (int k0 = 0; k0 < 1024; k0 += 32) {
    __syncthreads();
    #pragma unroll
    for (int i = 0; i < 2; ++i) {
      int sb = i * 256 + wbase;
      int s = sb + lane;
      int row = s >> 2, c = s & 3;
      async16(As + sb * 8, A + (long)(m0 + row) * 1024 + k0 + c * 8);
    }
    {
      int s = t;
      int row = s >> 2, c = s & 3;
      async16(Bs + wbase * 8, Bt + (long)(n0 + row) * 1024 + k0 + c * 8);
    }
    __syncthreads();
    bf16x8 af[2], bfr[4];
    #pragma unroll
    for (int mt = 0; mt < 2; ++mt)
      af[mt] = *(const bf16x8*)(As + (wave * 32 + mt * 16 + l16) * 32 + quad * 8);
    #pragma unroll
    for (int nt = 0; nt < 4; ++nt)
      bfr[nt] = *(const bf16x8*)(Bs + (nt * 16 + l16) * 32 + quad * 8);
    #pragma unroll
    for (int mt = 0; mt < 2; ++mt)
      #pragma unroll
      for (int nt = 0; nt < 4; ++nt)
        acc[mt][nt] = __builtin_amdgcn_mfma_f32_16x16x32_bf16(af[mt], bfr[nt], acc[mt][nt], 0, 0, 0);
  }
  #pragma unroll
  for (int mt = 0; mt < 2; ++mt)
    #pragma unroll
    for (int nt = 0; nt < 4; ++nt) {
      int col = n0 + nt * 16 + l16;
      #pragma unroll
      for (int r = 0; r < 4; ++r) {
        int row = m0 + wave * 32 + mt * 16 + quad * 4 + r;
        C[(long)row * 1024 + col] = acc[mt][nt][r] + bias[col];
      }
    }
}

// ---------------- flash attention v7 = R4 structure + stride-68 LDS --------
// 512 threads, q-tile 256 (32 rows/wave), grid 256 (bh in low 5 bits -> XCD
// L2 affinity). R4-proven loop: prefetch K/V(kt+1) into regs at top, compute
// kt, barrier, ds_write kt+1, barrier. All LDS rows stride 68 u16 (odd dword
// count) -> measured-0-conflict vector access pattern (R5). P lives in its
// own buffer (R4 aliased other waves' live Q rows - latent race, removed).
// Qp (B,L,H,64) pre-scaled by 0.125*log2(e). Kp (B,L,H,64). Vt (B*H,64,L).
__global__ __launch_bounds__(512, 2) void k_flash(const u16* __restrict__ Qp,
                                                  const u16* __restrict__ Kp,
                                                  const u16* __restrict__ Vt,
                                                  u16* __restrict__ ctx) {
  __shared__ __align__(16) u16 qs[256 * 68];    // Q tile
  __shared__ __align__(16) u16 ks[64 * 68];     // K tile [l][d]
  __shared__ __align__(16) u16 vs[64 * 68];     // V^T tile [d][l]
  __shared__ __align__(16) u16 ps[8 * 16 * 68]; // per-wave P (16 rows, reused per msub)
  const int t = threadIdx.x, lane = t & 63, quad = lane >> 4, l16 = lane & 15;
  const int wave = t >> 6;                      // 0..7
  const int bh = blockIdx.x & 31, b = bh >> 4, h = bh & 15;
  const int q0 = (blockIdx.x >> 5) * 256;
  const long gkbase = (long)b * 2097152 + h * 64;
  const long gvbase = (long)bh * 131072;
  const int srow = t >> 3, sc = t & 7;          // staging: 64 rows x 8 chunks

  // ---- startup: Q (256x64, 4 chunks/thread) + K/V tile 0, all reg-staged --
  const long gq = (long)(b * 2048 + q0) * 1024 + h * 64;
  {
    bf16x8 qr[4];
    #pragma unroll
    for (int i = 0; i < 4; ++i)
      qr[i] = *(const bf16x8*)(Qp + gq + (long)((i * 512 + t) >> 3) * 1024 + (t & 7) * 8);
    bf16x8 k0r = *(const bf16x8*)(Kp + gkbase + (long)srow * 1024 + sc * 8);
    bf16x8 v0r = *(const bf16x8*)(Vt + gvbase + (long)srow * 2048 + sc * 8);
    #pragma unroll
    for (int i = 0; i < 4; ++i)
      *(bf16x8*)(qs + (long)((i * 512 + t) >> 3) * 68 + (t & 7) * 8) = qr[i];
    *(bf16x8*)(ks + srow * 68 + sc * 8) = k0r;
    *(bf16x8*)(vs + srow * 68 + sc * 8) = v0r;
  }
  __syncthreads();

  bf16x8 qf[2][2];
  #pragma unroll
  for (int msub = 0; msub < 2; ++msub)
    #pragma unroll
    for (int kh = 0; kh < 2; ++kh)
      qf[msub][kh] = *(const bf16x8*)(qs + (wave * 32 + msub * 16 + l16) * 68 + kh * 32 + quad * 8);
  u16* pw = ps + wave * 1088;  // 16 rows x 68

  float lsum[2][4] = {};
  f32x4 o[2][4] = {};
  bf16x8 kreg, vreg;

  for (int kt = 0; kt < 32; ++kt) {
    // prefetch next K/V tile into regs; in flight across this compute phase,
    // drained at the ds_write after the first barrier (R4-proven overlap).
    if (kt < 31) {
      int kv0 = (kt + 1) * 64;
      kreg = *(const bf16x8*)(Kp + gkbase + (long)(kv0 + srow) * 1024 + sc * 8);
      vreg = *(const bf16x8*)(Vt + gvbase + kv0 + (long)srow * 2048 + sc * 8);
    }

    // K and V^T fragments (vector b128, stride-68 rows)
    bf16x8 kf[4][2], vf[4][2];
    #pragma unroll
    for (int nt = 0; nt < 4; ++nt)
      #pragma unroll
      for (int kh = 0; kh < 2; ++kh) {
        kf[nt][kh] = *(const bf16x8*)(ks + (nt * 16 + l16) * 68 + kh * 32 + quad * 8);
        vf[nt][kh] = *(const bf16x8*)(vs + (nt * 16 + l16) * 68 + kh * 32 + quad * 8);
      }

    #pragma unroll
    for (int msub = 0; msub < 2; ++msub) {
      // S(16x64) = Q @ K^T ; p = exp2(s) ; P row-major [q][kv] in own buffer
      #pragma unroll
      for (int nt = 0; nt < 4; ++nt) {
        f32x4 a = {};
        #pragma unroll
        for (int kh = 0; kh < 2; ++kh)
          a = __builtin_amdgcn_mfma_f32_16x16x32_bf16(qf[msub][kh], kf[nt][kh], a, 0, 0, 0);
        #pragma unroll
        for (int r = 0; r < 4; ++r) {
          float e = __builtin_amdgcn_exp2f(a[r]);
          lsum[msub][r] += e;
          pw[(quad * 4 + r) * 68 + nt * 16 + l16] = f2bf(e);
        }
      }
      // O(16x64) += P @ V  (same-wave DS ordering makes P visible)
      #pragma unroll
      for (int kh = 0; kh < 2; ++kh) {
        bf16x8 pa = *(const bf16x8*)(pw + l16 * 68 + kh * 32 + quad * 8);
        #pragma unroll
        for (int nt = 0; nt < 4; ++nt)
          o[msub][nt] = __builtin_amdgcn_mfma_f32_16x16x32_bf16(pa, vf[nt][kh], o[msub][nt], 0, 0, 0);
      }
    }

    __syncthreads();  // all waves done reading ks/vs; prefetch drained here
    if (kt < 31) {
      *(bf16x8*)(ks + srow * 68 + sc * 8) = kreg;
      *(bf16x8*)(vs + srow * 68 + sc * 8) = vreg;
    }
    __syncthreads();  // next tile visible
  }

  // final l reduction across the 16 kv-lanes, then normalize + write
  #pragma unroll
  for (int msub = 0; msub < 2; ++msub)
    #pragma unroll
    for (int r = 0; r < 4; ++r) {
      float l = lsum[msub][r];
      #pragma unroll
      for (int d = 1; d < 16; d <<= 1) l += __shfl_xor(l, d);
      lsum[msub][r] = 1.0f / l;
    }
  #pragma unroll
  for (int msub = 0; msub < 2; ++msub)
    #pragma unroll
    for (int nt = 0; nt < 4; ++nt)
      #pragma unroll
      for (int r = 0; r < 4; ++r) {
        int q = q0 + wave * 32 + msub * 16 + quad * 4 + r;
        long idx = (long)(b * 2048 + q) * 1024 + h * 64 + nt * 16 + l16;
        ctx[idx] = f2bf(o[msub][nt][r] * lsum[msub][r]);
      }
}

extern "C" void kernel_launch(void* const* d_in, const int* in_sizes, int n_in,
                              void* d_out, int out_size, void* d_ws, size_t ws_size,
                              hipStream_t stream) {
  const float* query = (const float*)d_in[0];
  const float* key   = (const float*)d_in[1];
  const float* value = (const float*)d_in[2];
  const float* Wq    = (const float*)d_in[3];
  const float* Wk    = (const float*)d_in[4];
  const float* Wv    = (const float*)d_in[5];
  const float* out_w = (const float*)d_in[6];
  const float* out_b = (const float*)d_in[7];
  // d_in[8] = coupling: unused — per-head scalar bias is softmax-invariant.
  float* out = (float*)d_out;

  char* ws = (char*)d_ws;
  size_t off = 0;
  auto alloc = [&](size_t bytes) {
    void* p = ws + off;
    off += (bytes + 255) & ~(size_t)255;
    return p;
  };
  // qb,kb,vb contiguous; wtq,wtk,wtv contiguous; Qp,Kp,Vp contiguous —
  // k_cast3 / k_transpose_w / k_gemm_qkv index them by z-stride.
  u16* qb  = (u16*)alloc(4096L * 1024 * 2);
  u16* kb  = (u16*)alloc(4096L * 1024 * 2);
  u16* vb  = (u16*)alloc(4096L * 1024 * 2);
  u16* wtq = (u16*)alloc(1024L * 1024 * 2);
  u16* wtk = (u16*)alloc(1024L * 1024 * 2);
  u16* wtv = (u16*)alloc(1024L * 1024 * 2);
  u16* wto = (u16*)alloc(1024L * 1024 * 2);
  u16* Qp  = (u16*)alloc(4096L * 1024 * 2);
  u16* Kp  = (u16*)alloc(4096L * 1024 * 2);
  u16* Vp  = (u16*)alloc(4096L * 1024 * 2);
  u16* Vtb = (u16*)alloc(4096L * 1024 * 2);
  u16* ctx = qb;  // reuse: query-bf16 dead after Q projection
  (void)kb; (void)vb; (void)wtk; (void)wtv; (void)Kp; (void)Vp;

  // inputs -> bf16 (fused, grid.y selects tensor)
  k_cast3<<<dim3(4096, 3), 256, 0, stream>>>(Ptr3{query, key, value}, qb);

  // Wq/Wk/Wv -> Bt (NxK) bf16 (fused).  wt[w][h*64+k][d] = W[w][h][d][k]
  k_transpose_w<<<dim3(16, 1, 48), 256, 0, stream>>>(Ptr3{Wq, Wk, Wv}, wtq);
  // out_w (K x N) -> wto (N x K)
  k_transpose_bf16<<<dim3(16, 16, 1), 256, 0, stream>>>(out_w, 1, wto, 1024, 1024, 1, 0L, 0L);

  // fused Q,K,V projections (Q pre-scaled by 0.125*log2(e))
  k_gemm_qkv<<<dim3(8, 32, 3), 256, 0, stream>>>(qb, wtq, Qp, QSCALE);

  // V -> V^T per (b,h): Vt[bh][dim][l]
  k_transpose_bf16<<<dim3(32, 1, 32), 256, 0, stream>>>(Vp, 0, Vtb, 1024, 2048, 16, 64L, 2097152L);

  // attention: grid 256 = 8 q-tiles x 32 bh, bh in low 5 bits for XCD affinity
  k_flash<<<256, 512, 0, stream>>>(Qp, Kp, Vtb, ctx);

  // output projection + bias -> f32
  k_gemm_out<<<dim3(16, 32), 256, 0, stream>>>(ctx, wto, out, out_b);
}

// Round 8
// 246.262 us; speedup vs baseline: 1.4216x; 1.0750x over previous
//
#include <hip/hip_runtime.h>
#include <cstdint>

typedef uint16_t u16;
typedef __attribute__((ext_vector_type(8))) short bf16x8;
typedef __attribute__((ext_vector_type(4))) short bf16x4;
typedef __attribute__((ext_vector_type(4))) float f32x4;

// 0.125 * log2(e): folded into Q projection so softmax is exp2(s) directly.
#define QSCALE 0.18033688011112042f

struct Ptr3 { const float* a; const float* b; const float* c; };

__device__ __forceinline__ u16 f2bf(float x) {
  union { float f; uint32_t u; } v; v.f = x;
  uint32_t r = (v.u + 0x7fffu + ((v.u >> 16) & 1u)) >> 16;
  return (u16)r;
}

// async global->LDS, 16B per lane. LDS dest is wave-uniform base + lane*16.
__device__ __forceinline__ void async16(void* lds, const void* g) {
  __builtin_amdgcn_global_load_lds((const __attribute__((address_space(1))) void*)g,
                                   (__attribute__((address_space(3))) void*)lds, 16, 0, 0);
}

// ---------------- fused elementwise f32 -> bf16 (3 tensors) ----------------
__global__ __launch_bounds__(256) void k_cast3(Ptr3 in, u16* __restrict__ out) {
  const int z = blockIdx.y;
  const float* p = z == 0 ? in.a : (z == 1 ? in.b : in.c);
  int i = blockIdx.x * 256 + threadIdx.x;
  float4 v = ((const float4*)p)[i];
  bf16x4 o;
  o[0] = (short)f2bf(v.x); o[1] = (short)f2bf(v.y);
  o[2] = (short)f2bf(v.z); o[3] = (short)f2bf(v.w);
  *(bf16x4*)(out + (long)z * 4194304 + (long)i * 4) = o;
}

// ------- fused weight transposes: Wq/Wk/Wv (768 blocks) + out_w (256) ------
// W[h][d][k] -> wt[w][h*64+k][d]; out_w (KxN) -> wto (NxK). stride 65 = odd.
__global__ __launch_bounds__(256) void k_transpose_all(Ptr3 w, const float* __restrict__ ow,
                                                       u16* __restrict__ wt,
                                                       u16* __restrict__ wto) {
  __shared__ u16 tile[64 * 65];
  const int t = threadIdx.x;
  const int bx = blockIdx.x;
  const float* in;
  long in_base, out_base;
  int rstr, r0, c0;
  u16* outp;
  if (bx < 768) {
    int z = bx >> 4;
    r0 = (bx & 15) * 64; c0 = 0;
    in = (z < 16) ? w.a : (z < 32 ? w.b : w.c);
    in_base = (long)(z & 15) * 65536;
    out_base = (long)z * 65536;
    rstr = 64; outp = wt;
  } else {
    int idx = bx - 768;
    r0 = (idx >> 4) * 64; c0 = (idx & 15) * 64;
    in = ow; in_base = 0; out_base = 0;
    rstr = 1024; outp = wto;
  }
  for (int e = t; e < 4096; e += 256) {
    int rr = e >> 6, cc = e & 63;
    tile[rr * 65 + cc] = f2bf(in[in_base + (long)(r0 + rr) * rstr + c0 + cc]);
  }
  __syncthreads();
  for (int s = t; s < 512; s += 256) {
    int cc = s >> 3, r8 = (s & 7) << 3;
    bf16x8 p;
    #pragma unroll
    for (int j = 0; j < 8; ++j) p[j] = (short)tile[(r8 + j) * 65 + cc];
    *(bf16x8*)(outp + out_base + (long)(c0 + cc) * 1024 + r0 + r8) = p;
  }
}

// ---------------- fused QKV GEMM: 128x128 tile, grid (8,32,3) --------------
// R4-proven async16 m97 structure. z<2: C bf16 = (A*Bt^T)*scale -> Qp/Kp.
// z==2: epilogue transposes the tile in LDS and writes Vt[bh][d][l] directly
// (coalesced along l) -- replaces the separate global V-transpose pass.
__global__ __launch_bounds__(256) void k_gemm_qkv(const u16* __restrict__ A0,
                                                  const u16* __restrict__ B0,
                                                  u16* __restrict__ C0,
                                                  u16* __restrict__ Vt, float scale0) {
  __shared__ __align__(16) u16 As[128 * 32];
  __shared__ __align__(16) u16 Bs[128 * 32];
  __shared__ u16 T[128 * 130];   // z==2 epilogue transpose tile (2-way banks)
  const int z = blockIdx.z;
  const u16* A = A0 + (long)z * 4194304;
  const u16* Bt = B0 + (long)z * 1048576;
  const int t = threadIdx.x, lane = t & 63, quad = lane >> 4, l16 = lane & 15;
  const int wave = t >> 6, wy = wave >> 1, wx = wave & 1;
  const int m0 = blockIdx.y * 128, n0 = blockIdx.x * 128;
  const int wbase = t & 192;
  f32x4 acc[4][4] = {};
  for (int k0 = 0; k0 < 1024; k0 += 32) {
    __syncthreads();
    #pragma unroll
    for (int i = 0; i < 2; ++i) {
      int sb = i * 256 + wbase;
      int s = sb + lane;
      int row = s >> 2, c = s & 3;
      async16(As + sb * 8, A + (long)(m0 + row) * 1024 + k0 + c * 8);
      async16(Bs + sb * 8, Bt + (long)(n0 + row) * 1024 + k0 + c * 8);
    }
    __syncthreads();
    bf16x8 af[4], bfr[4];
    #pragma unroll
    for (int mt = 0; mt < 4; ++mt)
      af[mt] = *(const bf16x8*)(As + (wy * 64 + mt * 16 + l16) * 32 + quad * 8);
    #pragma unroll
    for (int nt = 0; nt < 4; ++nt)
      bfr[nt] = *(const bf16x8*)(Bs + (wx * 64 + nt * 16 + l16) * 32 + quad * 8);
    #pragma unroll
    for (int mt = 0; mt < 4; ++mt)
      #pragma unroll
      for (int nt = 0; nt < 4; ++nt)
        acc[mt][nt] = __builtin_amdgcn_mfma_f32_16x16x32_bf16(af[mt], bfr[nt], acc[mt][nt], 0, 0, 0);
  }
  if (z < 2) {
    u16* C = C0 + (long)z * 4194304;
    const float scale = z ? 1.0f : scale0;
    #pragma unroll
    for (int mt = 0; mt < 4; ++mt)
      #pragma unroll
      for (int nt = 0; nt < 4; ++nt) {
        int col = n0 + wx * 64 + nt * 16 + l16;
        #pragma unroll
        for (int r = 0; r < 4; ++r) {
          int row = m0 + wy * 64 + mt * 16 + quad * 4 + r;
          C[(long)row * 1024 + col] = f2bf(acc[mt][nt][r] * scale);
        }
      }
  } else {
    // stage tile (rows=tokens lr, cols=2 heads x 64 dims) into LDS
    #pragma unroll
    for (int mt = 0; mt < 4; ++mt)
      #pragma unroll
      for (int nt = 0; nt < 4; ++nt) {
        int cc = wx * 64 + nt * 16 + l16;
        #pragma unroll
        for (int r = 0; r < 4; ++r)
          T[(wy * 64 + mt * 16 + quad * 4 + r) * 130 + cc] = f2bf(acc[mt][nt][r]);
      }
    __syncthreads();
    const int h0 = blockIdx.x * 2, bb = m0 >> 11, lb = m0 & 2047;
    #pragma unroll
    for (int i = 0; i < 8; ++i) {
      int s = t + i * 256;           // 0..2047 = 128 cols x 16 l-chunks
      int c = s >> 4, l0 = (s & 15) * 8;
      bf16x8 p;
      #pragma unroll
      for (int j = 0; j < 8; ++j) p[j] = (short)T[(l0 + j) * 130 + c];
      *(bf16x8*)(Vt + (long)(bb * 16 + h0 + (c >> 6)) * 131072 +
                 (long)(c & 63) * 2048 + lb + l0) = p;
    }
  }
}

// ---- out-proj GEMM: 128x64 tile, grid (16,32), async16, f32 out + bias ----
__global__ __launch_bounds__(256) void k_gemm_out(const u16* __restrict__ A,
                                                  const u16* __restrict__ Bt,
                                                  float* __restrict__ C,
                                                  const float* __restrict__ bias) {
  __shared__ __align__(16) u16 As[128 * 32];
  __shared__ __align__(16) u16 Bs[64 * 32];
  const int t = threadIdx.x, lane = t & 63, quad = lane >> 4, l16 = lane & 15;
  const int wave = t >> 6;
  const int m0 = blockIdx.y * 128, n0 = blockIdx.x * 64;
  const int wbase = t & 192;
  f32x4 acc[2][4] = {};
  for (int k0 = 0; k0 < 1024; k0 += 32) {
    __syncthreads();
    #pragma unroll
    for (int i = 0; i < 2; ++i) {
      int sb = i * 256 + wbase;
      int s = sb + lane;
      int row = s >> 2, c = s & 3;
      async16(As + sb * 8, A + (long)(m0 + row) * 1024 + k0 + c * 8);
    }
    {
      int s = t;
      int row = s >> 2, c = s & 3;
      async16(Bs + wbase * 8, Bt + (long)(n0 + row) * 1024 + k0 + c * 8);
    }
    __syncthreads();
    bf16x8 af[2], bfr[4];
    #pragma unroll
    for (int mt = 0; mt < 2; ++mt)
      af[mt] = *(const bf16x8*)(As + (wave * 32 + mt * 16 + l16) * 32 + quad * 8);
    #pragma unroll
    for (int nt = 0; nt < 4; ++nt)
      bfr[nt] = *(const bf16x8*)(Bs + (nt * 16 + l16) * 32 + quad * 8);
    #pragma unroll
    for (int mt = 0; mt < 2; ++mt)
      #pragma unroll
      for (int nt = 0; nt < 4; ++nt)
        acc[mt][nt] = __builtin_amdgcn_mfma_f32_16x16x32_bf16(af[mt], bfr[nt], acc[mt][nt], 0, 0, 0);
  }
  #pragma unroll
  for (int mt = 0; mt < 2; ++mt)
    #pragma unroll
    for (int nt = 0; nt < 4; ++nt) {
      int col = n0 + nt * 16 + l16;
      #pragma unroll
      for (int r = 0; r < 4; ++r) {
        int row = m0 + wave * 32 + mt * 16 + quad * 4 + r;
        C[(long)row * 1024 + col] = acc[mt][nt][r] + bias[col];
      }
    }
}

// ---------------- flash attention (R4-verbatim, the 64 us winner) ----------
// 512 threads, q-tile 256 (32 rows/wave). K/V staged via regs + ds_write
// (padded stride-72 rows). XCD-aware: bh = blockIdx&31 so all q-tiles of a
// head share one XCD's L2. Qp pre-scaled by 0.125*log2(e). Vt (B*H,64,L).
// NOTE (R7 lesson): do not touch this loop. Stride-68 / separate-P / dbuf /
// in-LDS V-transpose variants all measured slower (80/95/177 us vs 64).
__global__ __launch_bounds__(512, 2) void k_flash(const u16* __restrict__ Qp,
                                                  const u16* __restrict__ Kp,
                                                  const u16* __restrict__ Vt,
                                                  u16* __restrict__ ctx) {
  __shared__ __align__(16) u16 qs[256 * 64];   // 32KB Q stage; reused as P buffers
  __shared__ __align__(16) u16 ks[64 * 72];    // K tile, padded rows
  __shared__ __align__(16) u16 vs[64 * 72];    // V^T tile, padded rows
  const int t = threadIdx.x, lane = t & 63, quad = lane >> 4, l16 = lane & 15;
  const int wave = t >> 6;                      // 0..7
  const int bh = blockIdx.x & 31, b = bh >> 4, h = bh & 15;
  const int q0 = (blockIdx.x >> 5) * 256;
  const long gkbase = (long)b * 2097152 + h * 64;
  const long gvbase = (long)bh * 131072;
  const int srow = t >> 3, sc = t & 7;          // staging: row 0..63, 16B chunk 0..7

  // ---- startup: Q via async16 (XOR swizzle), K/V tile 0 via regs ----
  {
    long gq = (long)(b * 2048 + q0) * 1024 + h * 64;
    #pragma unroll
    for (int i = 0; i < 4; ++i) {
      int s = i * 512 + t;
      int row = s >> 3, pos = s & 7, c = pos ^ (row & 7);
      async16(qs + (long)s * 8, Qp + gq + (long)row * 1024 + c * 8);
    }
  }
  bf16x8 kreg = *(const bf16x8*)(Kp + gkbase + (long)srow * 1024 + sc * 8);
  bf16x8 vreg = *(const bf16x8*)(Vt + gvbase + (long)srow * 2048 + sc * 8);
  __syncthreads();  // Q visible

  bf16x8 qf[2][2];
  #pragma unroll
  for (int msub = 0; msub < 2; ++msub)
    #pragma unroll
    for (int kh = 0; kh < 2; ++kh) {
      int m = wave * 32 + msub * 16 + l16;
      int pos = (kh * 4 + quad) ^ (m & 7);
      qf[msub][kh] = *(const bf16x8*)(qs + m * 64 + pos * 8);
    }
  *(bf16x8*)(ks + srow * 72 + sc * 8) = kreg;
  *(bf16x8*)(vs + srow * 72 + sc * 8) = vreg;
  __syncthreads();  // K/V tile 0 visible; all qf reads drained -> qs safe as P

  u16* pw = qs + wave * 1152;  // per-wave P tile: 16 q-rows x 72 (one msub at a time)

  float lsum[2][4] = {};
  f32x4 o[2][4] = {};

  for (int kt = 0; kt < 32; ++kt) {
    // register prefetch of next K/V tile (in flight across this compute phase)
    if (kt < 31) {
      int kv0 = (kt + 1) * 64;
      kreg = *(const bf16x8*)(Kp + gkbase + (long)(kv0 + srow) * 1024 + sc * 8);
      vreg = *(const bf16x8*)(Vt + gvbase + kv0 + (long)srow * 2048 + sc * 8);
    }

    // K and V^T fragments (vector b128, <=2-way banks)
    bf16x8 kf[4][2], vf[4][2];
    #pragma unroll
    for (int nt = 0; nt < 4; ++nt)
      #pragma unroll
      for (int kh = 0; kh < 2; ++kh) {
        kf[nt][kh] = *(const bf16x8*)(ks + (nt * 16 + l16) * 72 + kh * 32 + quad * 8);
        vf[nt][kh] = *(const bf16x8*)(vs + (nt * 16 + l16) * 72 + kh * 32 + quad * 8);
      }

    #pragma unroll
    for (int msub = 0; msub < 2; ++msub) {
      // S(16x64) = Q @ K^T ; p = exp2(s); write P row-major [q][kv] to LDS
      #pragma unroll
      for (int nt = 0; nt < 4; ++nt) {
        f32x4 a = {};
        #pragma unroll
        for (int kh = 0; kh < 2; ++kh)
          a = __builtin_amdgcn_mfma_f32_16x16x32_bf16(qf[msub][kh], kf[nt][kh], a, 0, 0, 0);
        #pragma unroll
        for (int r = 0; r < 4; ++r) {
          float e = __builtin_amdgcn_exp2f(a[r]);
          lsum[msub][r] += e;
          pw[(quad * 4 + r) * 72 + nt * 16 + l16] = f2bf(e);
        }
      }
      // O(16x64) += P @ V : A-frag = contiguous b128 rows of P
      #pragma unroll
      for (int kh = 0; kh < 2; ++kh) {
        bf16x8 pa = *(const bf16x8*)(pw + l16 * 72 + kh * 32 + quad * 8);
        #pragma unroll
        for (int nt = 0; nt < 4; ++nt)
          o[msub][nt] = __builtin_amdgcn_mfma_f32_16x16x32_bf16(pa, vf[nt][kh], o[msub][nt], 0, 0, 0);
      }
    }

    __syncthreads();  // all waves done reading ks/vs (and prefetch drained)
    if (kt < 31) {
      *(bf16x8*)(ks + srow * 72 + sc * 8) = kreg;
      *(bf16x8*)(vs + srow * 72 + sc * 8) = vreg;
    }
    __syncthreads();  // next tile visible
  }

  // final l reduction across the 16 kv-lanes, then normalize + write
  #pragma unroll
  for (int msub = 0; msub < 2; ++msub)
    #pragma unroll
    for (int r = 0; r < 4; ++r) {
      float l = lsum[msub][r];
      #pragma unroll
      for (int d = 1; d < 16; d <<= 1) l += __shfl_xor(l, d);
      lsum[msub][r] = 1.0f / l;
    }
  #pragma unroll
  for (int msub = 0; msub < 2; ++msub)
    #pragma unroll
    for (int nt = 0; nt < 4; ++nt)
      #pragma unroll
      for (int r = 0; r < 4; ++r) {
        int q = q0 + wave * 32 + msub * 16 + quad * 4 + r;
        long idx = (long)(b * 2048 + q) * 1024 + h * 64 + nt * 16 + l16;
        ctx[idx] = f2bf(o[msub][nt][r] * lsum[msub][r]);
      }
}

extern "C" void kernel_launch(void* const* d_in, const int* in_sizes, int n_in,
                              void* d_out, int out_size, void* d_ws, size_t ws_size,
                              hipStream_t stream) {
  const float* query = (const float*)d_in[0];
  const float* key   = (const float*)d_in[1];
  const float* value = (const float*)d_in[2];
  const float* Wq    = (const float*)d_in[3];
  const float* Wk    = (const float*)d_in[4];
  const float* Wv    = (const float*)d_in[5];
  const float* out_w = (const float*)d_in[6];
  const float* out_b = (const float*)d_in[7];
  // d_in[8] = coupling: unused — per-head scalar bias is softmax-invariant.
  float* out = (float*)d_out;

  char* ws = (char*)d_ws;
  size_t off = 0;
  auto alloc = [&](size_t bytes) {
    void* p = ws + off;
    off += (bytes + 255) & ~(size_t)255;
    return p;
  };
  // qb,kb,vb contiguous (k_cast3 z-stride); wtq..wtv contiguous
  // (k_transpose_all z-stride); Qp,Kp contiguous (k_gemm_qkv z<2 stride).
  u16* qb  = (u16*)alloc(4096L * 1024 * 2);
  u16* kb  = (u16*)alloc(4096L * 1024 * 2);
  u16* vb  = (u16*)alloc(4096L * 1024 * 2);
  u16* wtq = (u16*)alloc(1024L * 1024 * 2);
  u16* wtk = (u16*)alloc(1024L * 1024 * 2);
  u16* wtv = (u16*)alloc(1024L * 1024 * 2);
  u16* wto = (u16*)alloc(1024L * 1024 * 2);
  u16* Qp  = (u16*)alloc(4096L * 1024 * 2);
  u16* Kp  = (u16*)alloc(4096L * 1024 * 2);
  u16* Vtb = (u16*)alloc(4096L * 1024 * 2);
  u16* ctx = qb;  // reuse: query-bf16 dead after Q projection
  (void)kb; (void)vb; (void)wtk; (void)wtv; (void)Kp;

  // inputs -> bf16 (fused, grid.y selects tensor)
  k_cast3<<<dim3(4096, 3), 256, 0, stream>>>(Ptr3{query, key, value}, qb);

  // all weight transposes in one launch (Wq/Wk/Wv -> wt*, out_w -> wto)
  k_transpose_all<<<1024, 256, 0, stream>>>(Ptr3{Wq, Wk, Wv}, out_w, wtq, wto);

  // fused Q,K,V projections; z==2 writes Vt[bh][d][l] directly (no V-transpose pass)
  k_gemm_qkv<<<dim3(8, 32, 3), 256, 0, stream>>>(qb, wtq, Qp, Vtb, QSCALE);

  // attention: grid 256 = 8 q-tiles x 32 bh, bh in low 5 bits for XCD affinity
  k_flash<<<256, 512, 0, stream>>>(Qp, Kp, Vtb, ctx);

  // output projection + bias -> f32
  k_gemm_out<<<dim3(16, 32), 256, 0, stream>>>(ctx, wto, out, out_b);
}

// Round 9
// 234.402 us; speedup vs baseline: 1.4936x; 1.0506x over previous
//
#include <hip/hip_runtime.h>
#include <cstdint>

typedef uint16_t u16;
typedef __attribute__((ext_vector_type(8))) short bf16x8;
typedef __attribute__((ext_vector_type(4))) short bf16x4;
typedef __attribute__((ext_vector_type(4))) float f32x4;

// 0.125 * log2(e): folded into Q projection so softmax is exp2(s) directly.
#define QSCALE 0.18033688011112042f

struct Ptr3 { const float* a; const float* b; const float* c; };

__device__ __forceinline__ u16 f2bf(float x) {
  union { float f; uint32_t u; } v; v.f = x;
  uint32_t r = (v.u + 0x7fffu + ((v.u >> 16) & 1u)) >> 16;
  return (u16)r;
}

// packed f32x2 -> bf16x2 (low = a, high = b). gfx950 has a HW instruction.
#if __has_builtin(__builtin_amdgcn_cvt_pk_bf16_f32)
typedef __bf16 bf2_t __attribute__((ext_vector_type(2)));
__device__ __forceinline__ uint32_t pkbf(float a, float b) {
  bf2_t v = __builtin_amdgcn_cvt_pk_bf16_f32(a, b);
  uint32_t u;
  __builtin_memcpy(&u, &v, 4);
  return u;
}
#else
__device__ __forceinline__ uint32_t pkbf(float a, float b) {
  return (uint32_t)f2bf(a) | ((uint32_t)f2bf(b) << 16);
}
#endif

// async global->LDS, 16B per lane. LDS dest is wave-uniform base + lane*16.
__device__ __forceinline__ void async16(void* lds, const void* g) {
  __builtin_amdgcn_global_load_lds((const __attribute__((address_space(1))) void*)g,
                                   (__attribute__((address_space(3))) void*)lds, 16, 0, 0);
}

// -------- fused pre-pass: input casts (12288 blocks) + weight transposes ---
// bx<12288: f32->bf16 cast of q/k/v. bx>=12288: 1024 transpose blocks
// (768 for Wq/Wk/Wv -> wt[w][h*64+k][d], 256 for out_w (KxN) -> wto (NxK)).
__global__ __launch_bounds__(256) void k_prep(Ptr3 in, u16* __restrict__ out,
                                              Ptr3 w, const float* __restrict__ ow,
                                              u16* __restrict__ wt, u16* __restrict__ wto) {
  __shared__ u16 tile[64 * 65];
  const int t = threadIdx.x;
  const int bx = blockIdx.x;
  if (bx < 12288) {
    int z = bx >> 12;
    int i = (bx & 4095) * 256 + t;
    const float* p = z == 0 ? in.a : (z == 1 ? in.b : in.c);
    float4 v = ((const float4*)p)[i];
    uint2 o2;
    o2.x = pkbf(v.x, v.y);
    o2.y = pkbf(v.z, v.w);
    *(uint2*)(out + (long)z * 4194304 + (long)i * 4) = o2;
    return;
  }
  const int b2 = bx - 12288;
  const float* src;
  long in_base, out_base;
  int rstr, r0, c0;
  u16* outp;
  if (b2 < 768) {
    int z = b2 >> 4;
    r0 = (b2 & 15) * 64; c0 = 0;
    src = (z < 16) ? w.a : (z < 32 ? w.b : w.c);
    in_base = (long)(z & 15) * 65536;
    out_base = (long)z * 65536;
    rstr = 64; outp = wt;
  } else {
    int idx = b2 - 768;
    r0 = (idx >> 4) * 64; c0 = (idx & 15) * 64;
    src = ow; in_base = 0; out_base = 0;
    rstr = 1024; outp = wto;
  }
  for (int e = t; e < 4096; e += 256) {
    int rr = e >> 6, cc = e & 63;
    tile[rr * 65 + cc] = f2bf(src[in_base + (long)(r0 + rr) * rstr + c0 + cc]);
  }
  __syncthreads();
  for (int s = t; s < 512; s += 256) {
    int cc = s >> 3, r8 = (s & 7) << 3;
    bf16x8 p;
    #pragma unroll
    for (int j = 0; j < 8; ++j) p[j] = (short)tile[(r8 + j) * 65 + cc];
    *(bf16x8*)(outp + out_base + (long)(c0 + cc) * 1024 + r0 + r8) = p;
  }
}

// ---------------- fused QKV GEMM: 128x128 tile, BK=64, grid (8,32,3) -------
// async16 staging with XOR-chunk swizzle (LDS pos p of row holds global chunk
// p^(row&7); flat stride 64 -> 2-way banks = free, async16-compatible).
// BK=64 halves barrier count vs BK=32. z<2: C bf16 = (A*Bt^T)*scale.
// z==2: epilogue transposes tile via LDS (T overlays As/Bs - dead after
// K-loop) and writes Vt[bh][d][l] directly.
__global__ __launch_bounds__(256) void k_gemm_qkv(const u16* __restrict__ A0,
                                                  const u16* __restrict__ B0,
                                                  u16* __restrict__ C0,
                                                  u16* __restrict__ Vt, float scale0) {
  __shared__ __align__(16) u16 smem[16640];   // As[0:8192) Bs[8192:16384) T[0:16640)
  u16* As = smem;
  u16* Bs = smem + 8192;
  u16* T  = smem;                             // z==2 epilogue only (128 x 130)
  const int z = blockIdx.z;
  const u16* A = A0 + (long)z * 4194304;
  const u16* Bt = B0 + (long)z * 1048576;
  const int t = threadIdx.x, lane = t & 63, quad = lane >> 4, l16 = lane & 15;
  const int wave = t >> 6, wy = wave >> 1, wx = wave & 1;
  const int m0 = blockIdx.y * 128, n0 = blockIdx.x * 128;
  const int wbase = t & 192;
  f32x4 acc[4][4] = {};
  for (int k0 = 0; k0 < 1024; k0 += 64) {
    __syncthreads();
    #pragma unroll
    for (int i = 0; i < 4; ++i) {
      int sb = i * 256 + wbase;
      int s = sb + lane;
      int row = s >> 3, c = s & 7;
      int cs = c ^ (row & 7);              // source chunk for LDS pos c
      async16(As + sb * 8, A + (long)(m0 + row) * 1024 + k0 + cs * 8);
      async16(Bs + sb * 8, Bt + (long)(n0 + row) * 1024 + k0 + cs * 8);
    }
    __syncthreads();
    #pragma unroll
    for (int kk = 0; kk < 2; ++kk) {
      bf16x8 af[4], bfr[4];
      #pragma unroll
      for (int mt = 0; mt < 4; ++mt) {
        int row = wy * 64 + mt * 16 + l16;
        int pos = (kk * 4 + quad) ^ (row & 7);
        af[mt] = *(const bf16x8*)(As + row * 64 + pos * 8);
      }
      #pragma unroll
      for (int nt = 0; nt < 4; ++nt) {
        int row = wx * 64 + nt * 16 + l16;
        int pos = (kk * 4 + quad) ^ (row & 7);
        bfr[nt] = *(const bf16x8*)(Bs + row * 64 + pos * 8);
      }
      #pragma unroll
      for (int mt = 0; mt < 4; ++mt)
        #pragma unroll
        for (int nt = 0; nt < 4; ++nt)
          acc[mt][nt] = __builtin_amdgcn_mfma_f32_16x16x32_bf16(af[mt], bfr[nt], acc[mt][nt], 0, 0, 0);
    }
  }
  if (z < 2) {
    u16* C = C0 + (long)z * 4194304;
    const float scale = z ? 1.0f : scale0;
    #pragma unroll
    for (int mt = 0; mt < 4; ++mt)
      #pragma unroll
      for (int nt = 0; nt < 4; ++nt) {
        int col = n0 + wx * 64 + nt * 16 + l16;
        int row = m0 + wy * 64 + mt * 16 + quad * 4;
        uint32_t ua = pkbf(acc[mt][nt][0] * scale, acc[mt][nt][1] * scale);
        uint32_t ub = pkbf(acc[mt][nt][2] * scale, acc[mt][nt][3] * scale);
        C[(long)row * 1024 + col] = (u16)ua;
        C[(long)(row + 1) * 1024 + col] = (u16)(ua >> 16);
        C[(long)(row + 2) * 1024 + col] = (u16)ub;
        C[(long)(row + 3) * 1024 + col] = (u16)(ub >> 16);
      }
  } else {
    __syncthreads();  // all waves done reading As/Bs before T overlays them
    #pragma unroll
    for (int mt = 0; mt < 4; ++mt)
      #pragma unroll
      for (int nt = 0; nt < 4; ++nt) {
        int cc = wx * 64 + nt * 16 + l16;
        int rr = wy * 64 + mt * 16 + quad * 4;
        uint32_t ua = pkbf(acc[mt][nt][0], acc[mt][nt][1]);
        uint32_t ub = pkbf(acc[mt][nt][2], acc[mt][nt][3]);
        T[(rr + 0) * 130 + cc] = (u16)ua;
        T[(rr + 1) * 130 + cc] = (u16)(ua >> 16);
        T[(rr + 2) * 130 + cc] = (u16)ub;
        T[(rr + 3) * 130 + cc] = (u16)(ub >> 16);
      }
    __syncthreads();
    const int h0 = blockIdx.x * 2, bb = m0 >> 11, lb = m0 & 2047;
    #pragma unroll
    for (int i = 0; i < 8; ++i) {
      int s = t + i * 256;           // 0..2047 = 128 cols x 16 l-chunks
      int c = s >> 4, l0 = (s & 15) * 8;
      bf16x8 p;
      #pragma unroll
      for (int j = 0; j < 8; ++j) p[j] = (short)T[(l0 + j) * 130 + c];
      *(bf16x8*)(Vt + (long)(bb * 16 + h0 + (c >> 6)) * 131072 +
                 (long)(c & 63) * 2048 + lb + l0) = p;
    }
  }
}

// ---- out-proj GEMM: 128x64 tile, grid (16,32), async16, f32 out + bias ----
// (R8-verbatim)
__global__ __launch_bounds__(256) void k_gemm_out(const u16* __restrict__ A,
                                                  const u16* __restrict__ Bt,
                                                  float* __restrict__ C,
                                                  const float* __restrict__ bias) {
  __shared__ __align__(16) u16 As[128 * 32];
  __shared__ __align__(16) u16 Bs[64 * 32];
  const int t = threadIdx.x, lane = t & 63, quad = lane >> 4, l16 = lane & 15;
  const int wave = t >> 6;
  const int m0 = blockIdx.y * 128, n0 = blockIdx.x * 64;
  const int wbase = t & 192;
  f32x4 acc[2][4] = {};
  for (int k0 = 0; k0 < 1024; k0 += 32) {
    __syncthreads();
    #pragma unroll
    for (int i = 0; i < 2; ++i) {
      int sb = i * 256 + wbase;
      int s = sb + lane;
      int row = s >> 2, c = s & 3;
      async16(As + sb * 8, A + (long)(m0 + row) * 1024 + k0 + c * 8);
    }
    {
      int s = t;
      int row = s >> 2, c = s & 3;
      async16(Bs + wbase * 8, Bt + (long)(n0 + row) * 1024 + k0 + c * 8);
    }
    __syncthreads();
    bf16x8 af[2], bfr[4];
    #pragma unroll
    for (int mt = 0; mt < 2; ++mt)
      af[mt] = *(const bf16x8*)(As + (wave * 32 + mt * 16 + l16) * 32 + quad * 8);
    #pragma unroll
    for (int nt = 0; nt < 4; ++nt)
      bfr[nt] = *(const bf16x8*)(Bs + (nt * 16 + l16) * 32 + quad * 8);
    #pragma unroll
    for (int mt = 0; mt < 2; ++mt)
      #pragma unroll
      for (int nt = 0; nt < 4; ++nt)
        acc[mt][nt] = __builtin_amdgcn_mfma_f32_16x16x32_bf16(af[mt], bfr[nt], acc[mt][nt], 0, 0, 0);
  }
  #pragma unroll
  for (int mt = 0; mt < 2; ++mt)
    #pragma unroll
    for (int nt = 0; nt < 4; ++nt) {
      int col = n0 + nt * 16 + l16;
      #pragma unroll
      for (int r = 0; r < 4; ++r) {
        int row = m0 + wave * 32 + mt * 16 + quad * 4 + r;
        C[(long)row * 1024 + col] = acc[mt][nt][r] + bias[col];
      }
    }
}

// ---------------- flash attention (R4 structure + packed bf16 cvt) ---------
// 512 threads, q-tile 256 (32 rows/wave). K/V staged via regs + ds_write
// (padded stride-72 rows). XCD-aware: bh = blockIdx&31. Qp pre-scaled by
// 0.125*log2(e). Vt (B*H,64,L). Loop structure is the proven 64us R4 winner
// (do NOT reschedule - R5/R6/R7 all regressed); this round only swaps the
// 3-op f2bf for the 1-inst packed cvt to cut VALU.
__global__ __launch_bounds__(512, 2) void k_flash(const u16* __restrict__ Qp,
                                                  const u16* __restrict__ Kp,
                                                  const u16* __restrict__ Vt,
                                                  u16* __restrict__ ctx) {
  __shared__ __align__(16) u16 qs[256 * 64];   // 32KB Q stage; reused as P buffers
  __shared__ __align__(16) u16 ks[64 * 72];    // K tile, padded rows
  __shared__ __align__(16) u16 vs[64 * 72];    // V^T tile, padded rows
  const int t = threadIdx.x, lane = t & 63, quad = lane >> 4, l16 = lane & 15;
  const int wave = t >> 6;                      // 0..7
  const int bh = blockIdx.x & 31, b = bh >> 4, h = bh & 15;
  const int q0 = (blockIdx.x >> 5) * 256;
  const long gkbase = (long)b * 2097152 + h * 64;
  const long gvbase = (long)bh * 131072;
  const int srow = t >> 3, sc = t & 7;          // staging: row 0..63, 16B chunk 0..7

  // ---- startup: Q via async16 (XOR swizzle), K/V tile 0 via regs ----
  {
    long gq = (long)(b * 2048 + q0) * 1024 + h * 64;
    #pragma unroll
    for (int i = 0; i < 4; ++i) {
      int s = i * 512 + t;
      int row = s >> 3, pos = s & 7, c = pos ^ (row & 7);
      async16(qs + (long)s * 8, Qp + gq + (long)row * 1024 + c * 8);
    }
  }
  bf16x8 kreg = *(const bf16x8*)(Kp + gkbase + (long)srow * 1024 + sc * 8);
  bf16x8 vreg = *(const bf16x8*)(Vt + gvbase + (long)srow * 2048 + sc * 8);
  __syncthreads();  // Q visible

  bf16x8 qf[2][2];
  #pragma unroll
  for (int msub = 0; msub < 2; ++msub)
    #pragma unroll
    for (int kh = 0; kh < 2; ++kh) {
      int m = wave * 32 + msub * 16 + l16;
      int pos = (kh * 4 + quad) ^ (m & 7);
      qf[msub][kh] = *(const bf16x8*)(qs + m * 64 + pos * 8);
    }
  *(bf16x8*)(ks + srow * 72 + sc * 8) = kreg;
  *(bf16x8*)(vs + srow * 72 + sc * 8) = vreg;
  __syncthreads();  // K/V tile 0 visible; all qf reads drained -> qs safe as P

  u16* pw = qs + wave * 1152;  // per-wave P tile: 16 q-rows x 72 (one msub at a time)

  float lsum[2][4] = {};
  f32x4 o[2][4] = {};

  for (int kt = 0; kt < 32; ++kt) {
    // register prefetch of next K/V tile (in flight across this compute phase)
    if (kt < 31) {
      int kv0 = (kt + 1) * 64;
      kreg = *(const bf16x8*)(Kp + gkbase + (long)(kv0 + srow) * 1024 + sc * 8);
      vreg = *(const bf16x8*)(Vt + gvbase + kv0 + (long)srow * 2048 + sc * 8);
    }

    // K and V^T fragments (vector b128, <=2-way banks)
    bf16x8 kf[4][2], vf[4][2];
    #pragma unroll
    for (int nt = 0; nt < 4; ++nt)
      #pragma unroll
      for (int kh = 0; kh < 2; ++kh) {
        kf[nt][kh] = *(const bf16x8*)(ks + (nt * 16 + l16) * 72 + kh * 32 + quad * 8);
        vf[nt][kh] = *(const bf16x8*)(vs + (nt * 16 + l16) * 72 + kh * 32 + quad * 8);
      }

    #pragma unroll
    for (int msub = 0; msub < 2; ++msub) {
      // S(16x64) = Q @ K^T ; p = exp2(s); write P row-major [q][kv] to LDS
      #pragma unroll
      for (int nt = 0; nt < 4; ++nt) {
        f32x4 a = {};
        #pragma unroll
        for (int kh = 0; kh < 2; ++kh)
          a = __builtin_amdgcn_mfma_f32_16x16x32_bf16(qf[msub][kh], kf[nt][kh], a, 0, 0, 0);
        float e0 = __builtin_amdgcn_exp2f(a[0]);
        float e1 = __builtin_amdgcn_exp2f(a[1]);
        float e2 = __builtin_amdgcn_exp2f(a[2]);
        float e3 = __builtin_amdgcn_exp2f(a[3]);
        lsum[msub][0] += e0; lsum[msub][1] += e1;
        lsum[msub][2] += e2; lsum[msub][3] += e3;
        uint32_t ua = pkbf(e0, e1), ub = pkbf(e2, e3);
        u16* pc = pw + (quad * 4) * 72 + nt * 16 + l16;
        pc[0]       = (u16)ua;
        pc[72]      = (u16)(ua >> 16);
        pc[144]     = (u16)ub;
        pc[216]     = (u16)(ub >> 16);
      }
      // O(16x64) += P @ V : A-frag = contiguous b128 rows of P
      #pragma unroll
      for (int kh = 0; kh < 2; ++kh) {
        bf16x8 pa = *(const bf16x8*)(pw + l16 * 72 + kh * 32 + quad * 8);
        #pragma unroll
        for (int nt = 0; nt < 4; ++nt)
          o[msub][nt] = __builtin_amdgcn_mfma_f32_16x16x32_bf16(pa, vf[nt][kh], o[msub][nt], 0, 0, 0);
      }
    }

    __syncthreads();  // all waves done reading ks/vs (and prefetch drained)
    if (kt < 31) {
      *(bf16x8*)(ks + srow * 72 + sc * 8) = kreg;
      *(bf16x8*)(vs + srow * 72 + sc * 8) = vreg;
    }
    __syncthreads();  // next tile visible
  }

  // final l reduction across the 16 kv-lanes, then normalize + write
  #pragma unroll
  for (int msub = 0; msub < 2; ++msub)
    #pragma unroll
    for (int r = 0; r < 4; ++r) {
      float l = lsum[msub][r];
      #pragma unroll
      for (int d = 1; d < 16; d <<= 1) l += __shfl_xor(l, d);
      lsum[msub][r] = 1.0f / l;
    }
  #pragma unroll
  for (int msub = 0; msub < 2; ++msub)
    #pragma unroll
    for (int nt = 0; nt < 4; ++nt) {
      int q = q0 + wave * 32 + msub * 16 + quad * 4;
      long idx = (long)(b * 2048 + q) * 1024 + h * 64 + nt * 16 + l16;
      uint32_t ua = pkbf(o[msub][nt][0] * lsum[msub][0], o[msub][nt][1] * lsum[msub][1]);
      uint32_t ub = pkbf(o[msub][nt][2] * lsum[msub][2], o[msub][nt][3] * lsum[msub][3]);
      ctx[idx]        = (u16)ua;
      ctx[idx + 1024] = (u16)(ua >> 16);
      ctx[idx + 2048] = (u16)ub;
      ctx[idx + 3072] = (u16)(ub >> 16);
    }
}

extern "C" void kernel_launch(void* const* d_in, const int* in_sizes, int n_in,
                              void* d_out, int out_size, void* d_ws, size_t ws_size,
                              hipStream_t stream) {
  const float* query = (const float*)d_in[0];
  const float* key   = (const float*)d_in[1];
  const float* value = (const float*)d_in[2];
  const float* Wq    = (const float*)d_in[3];
  const float* Wk    = (const float*)d_in[4];
  const float* Wv    = (const float*)d_in[5];
  const float* out_w = (const float*)d_in[6];
  const float* out_b = (const float*)d_in[7];
  // d_in[8] = coupling: unused — per-head scalar bias is softmax-invariant.
  float* out = (float*)d_out;

  char* ws = (char*)d_ws;
  size_t off = 0;
  auto alloc = [&](size_t bytes) {
    void* p = ws + off;
    off += (bytes + 255) & ~(size_t)255;
    return p;
  };
  // qb,kb,vb contiguous (k_prep cast z-stride); wtq..wtv contiguous
  // (k_prep transpose z-stride); Qp,Kp contiguous (k_gemm_qkv z<2 stride).
  u16* qb  = (u16*)alloc(4096L * 1024 * 2);
  u16* kb  = (u16*)alloc(4096L * 1024 * 2);
  u16* vb  = (u16*)alloc(4096L * 1024 * 2);
  u16* wtq = (u16*)alloc(1024L * 1024 * 2);
  u16* wtk = (u16*)alloc(1024L * 1024 * 2);
  u16* wtv = (u16*)alloc(1024L * 1024 * 2);
  u16* wto = (u16*)alloc(1024L * 1024 * 2);
  u16* Qp  = (u16*)alloc(4096L * 1024 * 2);
  u16* Kp  = (u16*)alloc(4096L * 1024 * 2);
  u16* Vtb = (u16*)alloc(4096L * 1024 * 2);
  u16* ctx = qb;  // reuse: query-bf16 dead after Q projection
  (void)kb; (void)vb; (void)wtk; (void)wtv; (void)Kp;

  // fused pre-pass: input casts + all weight transposes in one launch
  k_prep<<<13312, 256, 0, stream>>>(Ptr3{query, key, value}, qb,
                                    Ptr3{Wq, Wk, Wv}, out_w, wtq, wto);

  // fused Q,K,V projections; z==2 writes Vt[bh][d][l] directly
  k_gemm_qkv<<<dim3(8, 32, 3), 256, 0, stream>>>(qb, wtq, Qp, Vtb, QSCALE);

  // attention: grid 256 = 8 q-tiles x 32 bh, bh in low 5 bits for XCD affinity
  k_flash<<<256, 512, 0, stream>>>(Qp, Kp, Vtb, ctx);

  // output projection + bias -> f32
  k_gemm_out<<<dim3(16, 32), 256, 0, stream>>>(ctx, wto, out, out_b);
}